// Round 1
// baseline (462.407 us; speedup 1.0000x reference)
//
#include <hip/hip_runtime.h>
#include <math.h>

constexpr int kBS   = 32;
constexpr int kM    = 32768;
constexpr int kD    = 1024;
constexpr int kDE   = 128;
constexpr int kK    = 32;

// ---------------------------------------------------------------------------
// Kernel 1: q = unit_normalize(concat(x,y) @ Wq_em + b), q_cross = x @ Wq_cross + b
// grid: 32 (batch), block: 128 (one thread per output dim)
// ---------------------------------------------------------------------------
__global__ __launch_bounds__(128) void qproj_kernel(
    const float* __restrict__ x, const float* __restrict__ y,
    const float* __restrict__ Wqe, const float* __restrict__ bqe,
    const float* __restrict__ Wqc, const float* __restrict__ bqc,
    float* __restrict__ q, float* __restrict__ qc) {
  const int b = blockIdx.x;
  const int j = threadIdx.x;  // 0..127
  const float* xb = x + b * kD;
  const float* yb = y + b * kD;

  float a1[4] = {0.f, 0.f, 0.f, 0.f};
  float a2[4] = {0.f, 0.f, 0.f, 0.f};
  for (int i = 0; i < kD; i += 4) {
#pragma unroll
    for (int u = 0; u < 4; ++u) {
      float xv = xb[i + u];
      a1[u] += xv * Wqe[(size_t)(i + u) * kDE + j];
      a2[u] += xv * Wqc[(size_t)(i + u) * kDE + j];
    }
  }
  float b1[4] = {0.f, 0.f, 0.f, 0.f};
  for (int i = 0; i < kD; i += 4) {
#pragma unroll
    for (int u = 0; u < 4; ++u) {
      float yv = yb[i + u];
      b1[u] += yv * Wqe[(size_t)(kD + i + u) * kDE + j];
    }
  }
  float acc1 = (a1[0] + a1[1]) + (a1[2] + a1[3]) + (b1[0] + b1[1]) + (b1[2] + b1[3]);
  float acc2 = (a2[0] + a2[1]) + (a2[2] + a2[3]);
  acc1 += bqe[j];
  acc2 += bqc[j];

  // norm over 128 threads (2 waves)
  __shared__ float red[2];
  float sq = acc1 * acc1;
#pragma unroll
  for (int m = 1; m < 64; m <<= 1) sq += __shfl_xor(sq, m);
  if ((j & 63) == 0) red[j >> 6] = sq;
  __syncthreads();
  float tot = red[0] + red[1];
  float inv = 1.0f / sqrtf(tot + 1e-12f);
  q[b * kDE + j]  = acc1 * inv;
  qc[b * kDE + j] = acc2;
}

// ---------------------------------------------------------------------------
// Kernel 2: scores[b][m] = em_S[b][m] > 0 ? dot(q[b], em_K[b][m]) : -inf
// grid: (32 chunks, 32 batches), block: 256 (4 waves).
// Wave handles 256 contiguous rows; per iter 64 lanes x float4 = 2 rows (1KB).
// ---------------------------------------------------------------------------
__global__ __launch_bounds__(256) void scores_kernel(
    const float* __restrict__ emK, const float* __restrict__ emS,
    const float* __restrict__ q, float* __restrict__ sc) {
  const int b     = blockIdx.y;
  const int chunk = blockIdx.x;        // 0..31
  const int wave  = threadIdx.x >> 6;  // 0..3
  const int lane  = threadIdx.x & 63;
  const int half  = lane >> 5;         // 0/1 -> row parity
  const int l32   = lane & 31;

  const float4 qf = *reinterpret_cast<const float4*>(q + b * kDE + l32 * 4);
  const int rowbase = chunk * 1024 + wave * 256;
  const float* Kb = emK + (size_t)b * kM * kDE;
  const float* Sb = emS + (size_t)b * kM;
  float* scb = sc + (size_t)b * kM;

  for (int it = 0; it < 128; ++it) {
    const int row = rowbase + it * 2 + half;
    const float4 kv = *reinterpret_cast<const float4*>(Kb + (size_t)row * kDE + l32 * 4);
    float d = kv.x * qf.x + kv.y * qf.y + kv.z * qf.z + kv.w * qf.w;
    d += __shfl_xor(d, 1);
    d += __shfl_xor(d, 2);
    d += __shfl_xor(d, 4);
    d += __shfl_xor(d, 8);
    d += __shfl_xor(d, 16);
    if (l32 == 0) {
      float s = Sb[row];
      scb[row] = (s > 0.f) ? d : -INFINITY;
    }
  }
}

// ---------------------------------------------------------------------------
// Kernel 3: exact top-32 per batch (value desc, tie -> lower index).
// grid: 32, block: 1024. Thread t holds scores[j*1024+t], j=0..31 in registers.
// ---------------------------------------------------------------------------
__global__ __launch_bounds__(1024) void topk_kernel(
    const float* __restrict__ sc, float* __restrict__ topv, int* __restrict__ topi) {
  const int b = blockIdx.x;
  const int t = threadIdx.x;
  const float* scb = sc + (size_t)b * kM;

  float v[32];
#pragma unroll
  for (int j = 0; j < 32; ++j) v[j] = scb[j * 1024 + t];

  unsigned removed = 0u;
  float lmax;
  int lidx;
  auto rescan = [&]() {
    lmax = -INFINITY;
    lidx = 0x7fffffff;
#pragma unroll
    for (int j = 0; j < 32; ++j) {
      const bool alive = ((removed >> j) & 1u) == 0u;
      const float vj = v[j];
      const int mj = (j << 10) | t;
      if (alive && (vj > lmax || (vj == lmax && mj < lidx))) {
        lmax = vj;
        lidx = mj;
      }
    }
  };
  rescan();

  __shared__ float wv[16];
  __shared__ int wi[16];
  __shared__ float gv;
  __shared__ int gi;
  __shared__ float outv[32];
  __shared__ int outi[32];

  for (int k = 0; k < kK; ++k) {
    float rv = lmax;
    int ri = lidx;
#pragma unroll
    for (int m = 1; m < 64; m <<= 1) {
      float ov = __shfl_xor(rv, m);
      int oi = __shfl_xor(ri, m);
      if (ov > rv || (ov == rv && oi < ri)) { rv = ov; ri = oi; }
    }
    if ((t & 63) == 0) { wv[t >> 6] = rv; wi[t >> 6] = ri; }
    __syncthreads();
    if (t == 0) {
      float bv = wv[0];
      int bi = wi[0];
      for (int w = 1; w < 16; ++w) {
        if (wv[w] > bv || (wv[w] == bv && wi[w] < bi)) { bv = wv[w]; bi = wi[w]; }
      }
      gv = bv; gi = bi; outv[k] = bv; outi[k] = bi;
    }
    __syncthreads();
    const int widx = gi;
    (void)gv;
    if ((widx & 1023) == t) {   // owner rescans
      removed |= 1u << (widx >> 10);
      rescan();
    }
  }
  __syncthreads();
  if (t < kK) {
    topv[b * kK + t] = outv[t];
    topi[b * kK + t] = outi[t];
  }
}

// ---------------------------------------------------------------------------
// Kernel 4: gather V_top, cross-attn softmax, LN + FFN(GELU exact) + residual,
// final Wo projection. grid: 32, block: 256.
// ---------------------------------------------------------------------------
__global__ __launch_bounds__(256) void finish_kernel(
    const float* __restrict__ emV, const float* __restrict__ qc,
    const float* __restrict__ topv, const int* __restrict__ topi,
    const float* __restrict__ lng, const float* __restrict__ lnb,
    const float* __restrict__ f1w, const float* __restrict__ f1b,
    const float* __restrict__ f2w, const float* __restrict__ f2b,
    const float* __restrict__ Wo, const float* __restrict__ Wob,
    float* __restrict__ out) {
  const int b = blockIdx.x;
  const int t = threadIdx.x;

  __shared__ float Vt[32][128];
  __shared__ float qcl[128];
  __shared__ int ids[32];
  __shared__ float tvs[32];
  __shared__ float wgt[32];
  __shared__ float h[128];
  __shared__ float y1[512];
  __shared__ float o2[128];
  __shared__ float red[8];

  if (t < 32) { ids[t] = topi[b * kK + t]; tvs[t] = topv[b * kK + t]; }
  if (t < 128) qcl[t] = qc[b * kDE + t];
  __syncthreads();

  const float* Vb = emV + (size_t)b * kM * kDE;
#pragma unroll
  for (int e = t; e < 32 * 128; e += 256) {
    const int r = e >> 7, c = e & 127;
    Vt[r][c] = Vb[(size_t)ids[r] * kDE + c];
  }
  __syncthreads();

  // attention logits: wave w handles rows w*8 .. w*8+7
  const int wave = t >> 6, lane = t & 63;
  for (int kk = 0; kk < 8; ++kk) {
    const int k = wave * 8 + kk;
    float p = Vt[k][2 * lane] * qcl[2 * lane] + Vt[k][2 * lane + 1] * qcl[2 * lane + 1];
#pragma unroll
    for (int m = 1; m < 64; m <<= 1) p += __shfl_xor(p, m);
    if (lane == 0) {
      const float tv = tvs[k];
      wgt[k] = (tv == -INFINITY) ? -INFINITY : (p * 0.08838834764831845f + tv);
    }
  }
  __syncthreads();

  // softmax over 32 logits (lanes 0..31 of wave 0), nan_to_num semantics
  if (t < 32) {
    const float lg = wgt[t];
    float mx = lg;
#pragma unroll
    for (int m = 1; m < 32; m <<= 1) mx = fmaxf(mx, __shfl_xor(mx, m));
    float e = (mx == -INFINITY) ? 0.f : __expf(lg - mx);
    e = (lg == -INFINITY) ? 0.f : e;
    float s = e;
#pragma unroll
    for (int m = 1; m < 32; m <<= 1) s += __shfl_xor(s, m);
    wgt[t] = (s > 0.f) ? e / s : 0.f;
  }
  __syncthreads();

  // out = sum_k w_k * V_top[k]
  float od = 0.f;
  if (t < 128) {
#pragma unroll 8
    for (int k = 0; k < 32; ++k) od += wgt[k] * Vt[k][t];
  }

  // layernorm over 128 dims
  float s1 = (t < 128) ? od : 0.f;
  float s2 = (t < 128) ? od * od : 0.f;
#pragma unroll
  for (int m = 1; m < 64; m <<= 1) {
    s1 += __shfl_xor(s1, m);
    s2 += __shfl_xor(s2, m);
  }
  if ((t & 63) == 0) { red[t >> 6] = s1; red[4 + (t >> 6)] = s2; }
  __syncthreads();
  const float sum1 = red[0] + red[1] + red[2] + red[3];
  const float sum2 = red[4] + red[5] + red[6] + red[7];
  const float mu = sum1 * (1.f / 128.f);
  const float var = sum2 * (1.f / 128.f) - mu * mu;
  const float rstd = 1.0f / sqrtf(var + 1e-5f);
  if (t < 128) h[t] = (od - mu) * rstd * lng[t] + lnb[t];
  __syncthreads();

  // ffn1 + exact GELU
  for (int j = t; j < 512; j += 256) {
    float acc = f1b[j];
#pragma unroll 8
    for (int d = 0; d < 128; ++d) acc += h[d] * f1w[(size_t)d * 512 + j];
    y1[j] = 0.5f * acc * (1.f + erff(acc * 0.7071067811865476f));
  }
  __syncthreads();

  // ffn2 + residual
  if (t < 128) {
    float acc = f2b[t];
#pragma unroll 8
    for (int j = 0; j < 512; ++j) acc += y1[j] * f2w[(size_t)j * 128 + t];
    o2[t] = od + acc;
  }
  __syncthreads();

  // final projection: 1024 outputs, 4 per thread
  float a0 = Wob[t], a1 = Wob[t + 256], a2 = Wob[t + 512], a3 = Wob[t + 768];
#pragma unroll 4
  for (int d = 0; d < 128; ++d) {
    const float hv = o2[d];
    a0 += hv * Wo[(size_t)d * kD + t];
    a1 += hv * Wo[(size_t)d * kD + t + 256];
    a2 += hv * Wo[(size_t)d * kD + t + 512];
    a3 += hv * Wo[(size_t)d * kD + t + 768];
  }
  float* ob = out + b * kD;
  ob[t] = a0;
  ob[t + 256] = a1;
  ob[t + 512] = a2;
  ob[t + 768] = a3;
}

// ---------------------------------------------------------------------------
extern "C" void kernel_launch(void* const* d_in, const int* in_sizes, int n_in,
                              void* d_out, int out_size, void* d_ws, size_t ws_size,
                              hipStream_t stream) {
  const float* x   = (const float*)d_in[0];
  const float* y   = (const float*)d_in[1];
  const float* emK = (const float*)d_in[2];
  const float* emV = (const float*)d_in[3];
  const float* emS = (const float*)d_in[4];
  const float* Wqe = (const float*)d_in[5];
  const float* bqe = (const float*)d_in[6];
  const float* Wqc = (const float*)d_in[7];
  const float* bqc = (const float*)d_in[8];
  const float* Wo  = (const float*)d_in[9];
  const float* Wob = (const float*)d_in[10];
  const float* lng = (const float*)d_in[11];
  const float* lnb = (const float*)d_in[12];
  const float* f1w = (const float*)d_in[13];
  const float* f1b = (const float*)d_in[14];
  const float* f2w = (const float*)d_in[15];
  const float* f2b = (const float*)d_in[16];
  float* out = (float*)d_out;

  float* ws   = (float*)d_ws;
  float* q    = ws;                      // 32*128
  float* qc   = ws + 4096;               // 32*128
  float* topv = ws + 8192;               // 32*32
  int*   topi = (int*)(ws + 9216);       // 32*32
  float* sc   = ws + 10240;              // 32*32768

  hipLaunchKernelGGL(qproj_kernel, dim3(32), dim3(128), 0, stream,
                     x, y, Wqe, bqe, Wqc, bqc, q, qc);
  hipLaunchKernelGGL(scores_kernel, dim3(32, 32), dim3(256), 0, stream,
                     emK, emS, q, sc);
  hipLaunchKernelGGL(topk_kernel, dim3(32), dim3(1024), 0, stream,
                     sc, topv, topi);
  hipLaunchKernelGGL(finish_kernel, dim3(32), dim3(256), 0, stream,
                     emV, qc, topv, topi, lng, lnb, f1w, f1b, f2w, f2b, Wo, Wob, out);
}

// Round 2
// 267.473 us; speedup vs baseline: 1.7288x; 1.7288x over previous
//
#include <hip/hip_runtime.h>
#include <math.h>

constexpr int kM  = 32768;
constexpr int kD  = 1024;
constexpr int kDE = 128;
constexpr int kK  = 32;

// ---------------------------------------------------------------------------
// Kernel 1: q = unit_normalize(concat(x,y) @ Wq_em + b), q_cross = x @ Wq_cross + b
// grid: 32 (batch), block: 1024. Split-K: slice s = t>>7 (8 slices), out dim j = t&127.
// ---------------------------------------------------------------------------
__global__ __launch_bounds__(1024) void qproj_kernel(
    const float* __restrict__ x, const float* __restrict__ y,
    const float* __restrict__ Wqe, const float* __restrict__ bqe,
    const float* __restrict__ Wqc, const float* __restrict__ bqc,
    float* __restrict__ q, float* __restrict__ qc) {
  const int b = blockIdx.x, t = threadIdx.x;
  const int s = t >> 7, j = t & 127;
  const float* xb = x + b * kD;
  const float* yb = y + b * kD;

  // acc1: rows s*256 .. s*256+255 of concat(x,y) against Wqe
  const float* src1 = (s < 4) ? xb : yb;
  const int off1 = (s < 4) ? s * 256 : s * 256 - 1024;
  const int wb1 = s * 256;
  float a1[4] = {0.f, 0.f, 0.f, 0.f};
#pragma unroll 4
  for (int i0 = 0; i0 < 256; i0 += 4) {
#pragma unroll
    for (int u = 0; u < 4; ++u)
      a1[u] += src1[off1 + i0 + u] * Wqe[(wb1 + i0 + u) * kDE + j];
  }
  // acc2: rows s*128 .. s*128+127 of x against Wqc
  const int r2 = s * 128;
  float a2[4] = {0.f, 0.f, 0.f, 0.f};
#pragma unroll 4
  for (int i0 = 0; i0 < 128; i0 += 4) {
#pragma unroll
    for (int u = 0; u < 4; ++u)
      a2[u] += xb[r2 + i0 + u] * Wqc[(r2 + i0 + u) * kDE + j];
  }

  __shared__ float p1[8][128];
  __shared__ float p2[8][128];
  __shared__ float redn[16];
  p1[s][j] = (a1[0] + a1[1]) + (a1[2] + a1[3]);
  p2[s][j] = (a2[0] + a2[1]) + (a2[2] + a2[3]);
  __syncthreads();

  float a = 0.f, c = 0.f;
  if (t < 128) {
    a = bqe[t];
    c = bqc[t];
#pragma unroll
    for (int ss = 0; ss < 8; ++ss) { a += p1[ss][t]; c += p2[ss][t]; }
  }
  float sq = a * a;
#pragma unroll
  for (int m = 1; m < 64; m <<= 1) sq += __shfl_xor(sq, m);
  if ((t & 63) == 0) redn[t >> 6] = sq;
  __syncthreads();
  if (t < 128) {
    const float inv = 1.f / sqrtf(redn[0] + redn[1] + 1e-12f);
    q[b * kDE + t] = a * inv;
    qc[b * kDE + t] = c;
  }
}

// ---------------------------------------------------------------------------
// Kernel 2: scores[b][m] = em_S>0 ? dot(q[b], em_K[b][m]) : -inf
// grid: (64 chunks, 32 batches), block 256 (4 waves). Wave covers 128 rows;
// per iter 8 rows: half-wave w/ 4 float4 loads in flight (unroll 2 -> 8).
// ---------------------------------------------------------------------------
__global__ __launch_bounds__(256) void scores_kernel(
    const float* __restrict__ emK, const float* __restrict__ emS,
    const float* __restrict__ q, float* __restrict__ sc) {
  const int b = blockIdx.y, chunk = blockIdx.x;
  const int wave = threadIdx.x >> 6;
  const int lane = threadIdx.x & 63;
  const int half = lane >> 5;
  const int l32 = lane & 31;

  const float4 qf = *reinterpret_cast<const float4*>(q + b * kDE + l32 * 4);
  const int rowbase = chunk * 512 + wave * 128;
  const float* Kb = emK + (size_t)b * kM * kDE;
  const float* Sb = emS + (size_t)b * kM;
  float* scb = sc + (size_t)b * kM;

#pragma unroll 2
  for (int it = 0; it < 16; ++it) {
    const int r0 = rowbase + it * 8 + half * 4;
    const float* p = Kb + (size_t)r0 * kDE + l32 * 4;
    const float4 k0 = *reinterpret_cast<const float4*>(p);
    const float4 k1 = *reinterpret_cast<const float4*>(p + kDE);
    const float4 k2 = *reinterpret_cast<const float4*>(p + 2 * kDE);
    const float4 k3 = *reinterpret_cast<const float4*>(p + 3 * kDE);
    float d0 = k0.x * qf.x + k0.y * qf.y + k0.z * qf.z + k0.w * qf.w;
    float d1 = k1.x * qf.x + k1.y * qf.y + k1.z * qf.z + k1.w * qf.w;
    float d2 = k2.x * qf.x + k2.y * qf.y + k2.z * qf.z + k2.w * qf.w;
    float d3 = k3.x * qf.x + k3.y * qf.y + k3.z * qf.z + k3.w * qf.w;
#pragma unroll
    for (int m = 1; m < 32; m <<= 1) {
      d0 += __shfl_xor(d0, m);
      d1 += __shfl_xor(d1, m);
      d2 += __shfl_xor(d2, m);
      d3 += __shfl_xor(d3, m);
    }
    if (l32 == 0) {
      const float4 sv = *reinterpret_cast<const float4*>(Sb + r0);
      float4 ov;
      ov.x = (sv.x > 0.f) ? d0 : -INFINITY;
      ov.y = (sv.y > 0.f) ? d1 : -INFINITY;
      ov.z = (sv.z > 0.f) ? d2 : -INFINITY;
      ov.w = (sv.w > 0.f) ? d3 : -INFINITY;
      *reinterpret_cast<float4*>(scb + r0) = ov;
    }
  }
}

// ---------------------------------------------------------------------------
// Kernel 3: fused exact top-32 (hierarchical) + gather + cross-attn softmax +
// LN + FFN(GELU exact) + residual + Wo projection. grid: 32, block: 1024.
// Stage A: each of 16 waves -> its top-32 of its 2048 elems (in-register).
// Stage B: wave 0 merges 512 candidates -> global top-32 (value desc, idx asc).
// ---------------------------------------------------------------------------
__global__ __launch_bounds__(1024) void select_finish_kernel(
    const float* __restrict__ sc, const float* __restrict__ emV,
    const float* __restrict__ qc,
    const float* __restrict__ lng, const float* __restrict__ lnb,
    const float* __restrict__ f1w, const float* __restrict__ f1b,
    const float* __restrict__ f2w, const float* __restrict__ f2b,
    const float* __restrict__ Wo, const float* __restrict__ Wob,
    float* __restrict__ out) {
  const int b = blockIdx.x, t = threadIdx.x;
  const int wave = t >> 6, lane = t & 63;
  const float* scb = sc + (size_t)b * kM;

  __shared__ float candV[16 * 32];
  __shared__ int candI[16 * 32];
  __shared__ float outvS[32];
  __shared__ int outiS[32];
  __shared__ float Vt[32][128];
  __shared__ float qcl[128];
  __shared__ float wgt[32];
  __shared__ float hS[128];
  __shared__ float y1S[512];
  __shared__ float p2S[4][128];
  __shared__ float o2S[128];
  __shared__ float redA[16];
  __shared__ float redB[16];

  // ---- load 32 scores per thread (idx = j*1024 + t)
  float v[32];
#pragma unroll
  for (int j = 0; j < 32; ++j) v[j] = scb[j * 1024 + t];

  // ---- Stage A: per-wave top-32
  float bv = -INFINITY;
  int bj = 0;
#pragma unroll
  for (int j = 0; j < 32; ++j) {
    if (v[j] > bv) { bv = v[j]; bj = j; }
  }
  int bidx = bj * 1024 + t;

  for (int k = 0; k < kK; ++k) {
    float rv = bv;
    int ri = bidx;
#pragma unroll
    for (int m = 1; m < 64; m <<= 1) {
      const float ov = __shfl_xor(rv, m);
      const int oi = __shfl_xor(ri, m);
      if (ov > rv || (ov == rv && oi < ri)) { rv = ov; ri = oi; }
    }
    if (lane == 0) { candV[wave * 32 + k] = rv; candI[wave * 32 + k] = ri; }
    if (bidx == ri) {  // this lane owned the winner: clear + rescan
#pragma unroll
      for (int j = 0; j < 32; ++j)
        if (j == bj) v[j] = -INFINITY;
      bv = -INFINITY;
      bj = 0;
#pragma unroll
      for (int j = 0; j < 32; ++j) {
        if (v[j] > bv) { bv = v[j]; bj = j; }
      }
      bidx = bj * 1024 + t;
    }
  }
  __syncthreads();

  // ---- Stage B: wave 0 merges 16*32 candidates
  if (wave == 0) {
    float cv[8];
    int ci[8];
#pragma unroll
    for (int u = 0; u < 8; ++u) {
      cv[u] = candV[lane * 8 + u];
      ci[u] = candI[lane * 8 + u];
    }
    float b2 = -INFINITY;
    int bu = 0;
#pragma unroll
    for (int u = 0; u < 8; ++u) {
      if (cv[u] > b2 || (cv[u] == b2 && ci[u] < ci[bu])) { b2 = cv[u]; bu = u; }
    }
    int bi2 = ci[bu];
    for (int k = 0; k < kK; ++k) {
      float rv = b2;
      int ri = bi2;
#pragma unroll
      for (int m = 1; m < 64; m <<= 1) {
        const float ov = __shfl_xor(rv, m);
        const int oi = __shfl_xor(ri, m);
        if (ov > rv || (ov == rv && oi < ri)) { rv = ov; ri = oi; }
      }
      if (lane == 0) { outvS[k] = rv; outiS[k] = ri; }
      if (bi2 == ri) {
#pragma unroll
        for (int u = 0; u < 8; ++u)
          if (u == bu) cv[u] = -INFINITY;
        b2 = -INFINITY;
        bu = 0;
#pragma unroll
        for (int u = 0; u < 8; ++u) {
          if (cv[u] > b2 || (cv[u] == b2 && ci[u] < ci[bu])) { b2 = cv[u]; bu = u; }
        }
        bi2 = ci[bu];
      }
    }
  }
  if (t < 128) qcl[t] = qc[b * kDE + t];
  __syncthreads();

  // ---- gather V_top (32 rows x 128)
  const float* Vb = emV + (size_t)b * kM * kDE;
#pragma unroll
  for (int e = t; e < 32 * 128; e += 1024) {
    const int r = e >> 7, ccol = e & 127;
    Vt[r][ccol] = Vb[(size_t)outiS[r] * kDE + ccol];
  }
  __syncthreads();

  // ---- attention logits: 16 waves x 2 rows
#pragma unroll
  for (int kk = 0; kk < 2; ++kk) {
    const int k = wave * 2 + kk;
    float p = Vt[k][2 * lane] * qcl[2 * lane] + Vt[k][2 * lane + 1] * qcl[2 * lane + 1];
#pragma unroll
    for (int m = 1; m < 64; m <<= 1) p += __shfl_xor(p, m);
    if (lane == 0) {
      const float tv = outvS[k];
      wgt[k] = (tv == -INFINITY) ? -INFINITY : fmaf(p, 0.08838834764831845f, tv);
    }
  }
  __syncthreads();

  // ---- softmax over 32 logits (nan_to_num semantics)
  if (t < 32) {
    const float lg = wgt[t];
    float mx = lg;
#pragma unroll
    for (int m = 1; m < 32; m <<= 1) mx = fmaxf(mx, __shfl_xor(mx, m));
    float e = (mx == -INFINITY || lg == -INFINITY) ? 0.f : __expf(lg - mx);
    float ssum = e;
#pragma unroll
    for (int m = 1; m < 32; m <<= 1) ssum += __shfl_xor(ssum, m);
    wgt[t] = (ssum > 0.f) ? e / ssum : 0.f;
  }
  __syncthreads();

  // ---- out = sum_k w_k V_k (t < 128), then LayerNorm
  float od = 0.f;
  if (t < 128) {
#pragma unroll 8
    for (int k = 0; k < 32; ++k) od += wgt[k] * Vt[k][t];
  }
  float s1 = (t < 128) ? od : 0.f;
  float s2 = (t < 128) ? od * od : 0.f;
#pragma unroll
  for (int m = 1; m < 64; m <<= 1) {
    s1 += __shfl_xor(s1, m);
    s2 += __shfl_xor(s2, m);
  }
  if (lane == 0) { redA[wave] = s1; redB[wave] = s2; }
  __syncthreads();
  const float sum1 = redA[0] + redA[1];
  const float sum2 = redB[0] + redB[1];
  const float mu = sum1 * (1.f / 128.f);
  const float var = sum2 * (1.f / 128.f) - mu * mu;
  const float rstd = 1.f / sqrtf(var + 1e-5f);
  if (t < 128) hS[t] = (od - mu) * rstd * lng[t] + lnb[t];
  __syncthreads();

  // ---- FFN1 + exact GELU (512 outputs, one per thread t<512)
  if (t < 512) {
    float acc = f1b[t];
#pragma unroll 8
    for (int d = 0; d < 128; ++d) acc += hS[d] * f1w[(size_t)d * 512 + t];
    y1S[t] = 0.5f * acc * (1.f + erff(acc * 0.7071067811865476f));
  }
  __syncthreads();

  // ---- FFN2 split-K (4 slices of 128) into p2S
  if (t < 512) {
    const int g = t >> 7, ccol = t & 127;
    float acc = 0.f;
#pragma unroll 8
    for (int jj = 0; jj < 128; ++jj)
      acc += y1S[g * 128 + jj] * f2w[(size_t)(g * 128 + jj) * 128 + ccol];
    p2S[g][ccol] = acc;
  }
  __syncthreads();
  if (t < 128)
    o2S[t] = od + f2b[t] + ((p2S[0][t] + p2S[1][t]) + (p2S[2][t] + p2S[3][t]));
  __syncthreads();

  // ---- final projection: 1024 outputs, one per thread
  float acc = Wob[t];
#pragma unroll 8
  for (int d = 0; d < 128; ++d) acc += o2S[d] * Wo[(size_t)d * kD + t];
  out[(size_t)b * kD + t] = acc;
}

// ---------------------------------------------------------------------------
extern "C" void kernel_launch(void* const* d_in, const int* in_sizes, int n_in,
                              void* d_out, int out_size, void* d_ws, size_t ws_size,
                              hipStream_t stream) {
  const float* x   = (const float*)d_in[0];
  const float* y   = (const float*)d_in[1];
  const float* emK = (const float*)d_in[2];
  const float* emV = (const float*)d_in[3];
  const float* emS = (const float*)d_in[4];
  const float* Wqe = (const float*)d_in[5];
  const float* bqe = (const float*)d_in[6];
  const float* Wqc = (const float*)d_in[7];
  const float* bqc = (const float*)d_in[8];
  const float* Wo  = (const float*)d_in[9];
  const float* Wob = (const float*)d_in[10];
  const float* lng = (const float*)d_in[11];
  const float* lnb = (const float*)d_in[12];
  const float* f1w = (const float*)d_in[13];
  const float* f1b = (const float*)d_in[14];
  const float* f2w = (const float*)d_in[15];
  const float* f2b = (const float*)d_in[16];
  float* out = (float*)d_out;

  float* ws = (float*)d_ws;
  float* q  = ws;            // 32*128
  float* qc = ws + 4096;     // 32*128
  float* sc = ws + 8192;     // 32*32768 (16B-aligned)

  hipLaunchKernelGGL(qproj_kernel, dim3(32), dim3(1024), 0, stream,
                     x, y, Wqe, bqe, Wqc, bqc, q, qc);
  hipLaunchKernelGGL(scores_kernel, dim3(64, 32), dim3(256), 0, stream,
                     emK, emS, q, sc);
  hipLaunchKernelGGL(select_finish_kernel, dim3(32), dim3(1024), 0, stream,
                     sc, emV, qc, lng, lnb, f1w, f1b, f2w, f2b, Wo, Wob, out);
}

// Round 3
// 162.095 us; speedup vs baseline: 2.8527x; 1.6501x over previous
//
#include <hip/hip_runtime.h>
#include <math.h>

constexpr int kM  = 32768;
constexpr int kD  = 1024;
constexpr int kDE = 128;
constexpr int kK  = 32;
constexpr int kBins = 256;
constexpr int kCap  = 1024;   // candidate capacity in finish kernel

typedef float f4 __attribute__((ext_vector_type(4)));

__device__ __forceinline__ int score_bin(float s) {
  // scores are cosine sims in [-1,1]; -inf clamps to bin 0
  float u = s + 1.0f;
  float w = u * 128.0f;
  w = fminf(fmaxf(w, 0.0f), 255.0f);
  return (int)w;
}

// ---------------------------------------------------------------------------
// Kernel 1: q = unit_normalize(concat(x,y) @ Wq_em + b), q_cross = x @ Wq_cross + b
// Also zeroes the per-batch score histogram. grid 32, block 1024.
// ---------------------------------------------------------------------------
__global__ __launch_bounds__(1024) void qproj_kernel(
    const float* __restrict__ x, const float* __restrict__ y,
    const float* __restrict__ Wqe, const float* __restrict__ bqe,
    const float* __restrict__ Wqc, const float* __restrict__ bqc,
    float* __restrict__ q, float* __restrict__ qc,
    unsigned int* __restrict__ hist) {
  const int b = blockIdx.x, t = threadIdx.x;
  const int s = t >> 7, j = t & 127;

  if (t < kBins) hist[b * kBins + t] = 0u;  // zero hist for this batch

  const float* xb = x + b * kD;
  const float* yb = y + b * kD;

  const float* src1 = (s < 4) ? xb : yb;
  const int off1 = (s < 4) ? s * 256 : s * 256 - 1024;
  const int wb1 = s * 256;
  float a1[4] = {0.f, 0.f, 0.f, 0.f};
#pragma unroll 8
  for (int i0 = 0; i0 < 256; i0 += 4) {
#pragma unroll
    for (int u = 0; u < 4; ++u)
      a1[u] += src1[off1 + i0 + u] * Wqe[(wb1 + i0 + u) * kDE + j];
  }
  const int r2 = s * 128;
  float a2[4] = {0.f, 0.f, 0.f, 0.f};
#pragma unroll 8
  for (int i0 = 0; i0 < 128; i0 += 4) {
#pragma unroll
    for (int u = 0; u < 4; ++u)
      a2[u] += xb[r2 + i0 + u] * Wqc[(r2 + i0 + u) * kDE + j];
  }

  __shared__ float p1[8][128];
  __shared__ float p2[8][128];
  __shared__ float redn[2];
  p1[s][j] = (a1[0] + a1[1]) + (a1[2] + a1[3]);
  p2[s][j] = (a2[0] + a2[1]) + (a2[2] + a2[3]);
  __syncthreads();

  float a = 0.f, c = 0.f;
  if (t < 128) {
    a = bqe[t];
    c = bqc[t];
#pragma unroll
    for (int ss = 0; ss < 8; ++ss) { a += p1[ss][t]; c += p2[ss][t]; }
  }
  float sq = a * a;
#pragma unroll
  for (int m = 1; m < 64; m <<= 1) sq += __shfl_xor(sq, m);
  if (t == 0 || t == 64) redn[t >> 6] = sq;
  __syncthreads();
  if (t < 128) {
    const float inv = 1.f / sqrtf(redn[0] + redn[1] + 1e-12f);
    q[b * kDE + t] = a * inv;
    qc[b * kDE + t] = c;
  }
}

// ---------------------------------------------------------------------------
// Kernel 2: scores + per-batch histogram.
// grid (64 chunks, 32 batches), block 256 (4 waves). Wave covers 128 rows.
// Per iter: 16 rows (8 per 32-lane half), 8 x 1KB loads in flight, butterfly
// reduce broadcasts so lanes 0..7 own one row each (parallel store + hist).
// ---------------------------------------------------------------------------
__global__ __launch_bounds__(256) void scores_kernel(
    const float* __restrict__ emK, const float* __restrict__ emS,
    const float* __restrict__ q, float* __restrict__ sc,
    unsigned int* __restrict__ hist) {
  const int b = blockIdx.y, chunk = blockIdx.x;
  const int wave = threadIdx.x >> 6;
  const int lane = threadIdx.x & 63;
  const int half = lane >> 5;
  const int l32 = lane & 31;

  __shared__ unsigned int shist[kBins];
  if (threadIdx.x < kBins) shist[threadIdx.x] = 0u;
  __syncthreads();

  const float4 qf = *reinterpret_cast<const float4*>(q + b * kDE + l32 * 4);
  const int rowbase = chunk * 512 + wave * 128;
  const float* Kb = emK + (size_t)b * kM * kDE;
  const float* Sb = emS + (size_t)b * kM;
  float* scb = sc + (size_t)b * kM;

  for (int it = 0; it < 8; ++it) {
    const int A = rowbase + it * 16 + half * 8;  // this half's first row
    const float* p = Kb + (size_t)A * kDE + l32 * 4;
    const f4 k0 = __builtin_nontemporal_load((const f4*)(p));
    const f4 k1 = __builtin_nontemporal_load((const f4*)(p + kDE));
    const f4 k2 = __builtin_nontemporal_load((const f4*)(p + 2 * kDE));
    const f4 k3 = __builtin_nontemporal_load((const f4*)(p + 3 * kDE));
    const f4 k4 = __builtin_nontemporal_load((const f4*)(p + 4 * kDE));
    const f4 k5 = __builtin_nontemporal_load((const f4*)(p + 5 * kDE));
    const f4 k6 = __builtin_nontemporal_load((const f4*)(p + 6 * kDE));
    const f4 k7 = __builtin_nontemporal_load((const f4*)(p + 7 * kDE));

    float d0 = fmaf(k0.w, qf.w, fmaf(k0.z, qf.z, fmaf(k0.y, qf.y, k0.x * qf.x)));
    float d1 = fmaf(k1.w, qf.w, fmaf(k1.z, qf.z, fmaf(k1.y, qf.y, k1.x * qf.x)));
    float d2 = fmaf(k2.w, qf.w, fmaf(k2.z, qf.z, fmaf(k2.y, qf.y, k2.x * qf.x)));
    float d3 = fmaf(k3.w, qf.w, fmaf(k3.z, qf.z, fmaf(k3.y, qf.y, k3.x * qf.x)));
    float d4 = fmaf(k4.w, qf.w, fmaf(k4.z, qf.z, fmaf(k4.y, qf.y, k4.x * qf.x)));
    float d5 = fmaf(k5.w, qf.w, fmaf(k5.z, qf.z, fmaf(k5.y, qf.y, k5.x * qf.x)));
    float d6 = fmaf(k6.w, qf.w, fmaf(k6.z, qf.z, fmaf(k6.y, qf.y, k6.x * qf.x)));
    float d7 = fmaf(k7.w, qf.w, fmaf(k7.z, qf.z, fmaf(k7.y, qf.y, k7.x * qf.x)));

#pragma unroll
    for (int m = 1; m < 32; m <<= 1) {
      d0 += __shfl_xor(d0, m);
      d1 += __shfl_xor(d1, m);
      d2 += __shfl_xor(d2, m);
      d3 += __shfl_xor(d3, m);
      d4 += __shfl_xor(d4, m);
      d5 += __shfl_xor(d5, m);
      d6 += __shfl_xor(d6, m);
      d7 += __shfl_xor(d7, m);
    }
    // lane l32 (<8) owns row A + l32
    const float e0 = (l32 & 1) ? d1 : d0;
    const float e1 = (l32 & 1) ? d3 : d2;
    const float e2 = (l32 & 1) ? d5 : d4;
    const float e3 = (l32 & 1) ? d7 : d6;
    const float g0 = (l32 & 2) ? e1 : e0;
    const float g1 = (l32 & 2) ? e3 : e2;
    const float sel = (l32 & 4) ? g1 : g0;

    const float sv = Sb[A + (l32 & 7)];
    const float val = (sv > 0.f) ? sel : -INFINITY;
    if (l32 < 8) {
      scb[A + l32] = val;
      atomicAdd(&shist[score_bin(val)], 1u);
    }
  }
  __syncthreads();
  if (threadIdx.x < kBins) {
    const unsigned int ccount = shist[threadIdx.x];
    if (ccount) atomicAdd(&hist[b * kBins + threadIdx.x], ccount);
  }
}

// ---------------------------------------------------------------------------
// Kernel 3: histogram threshold -> exact top-32 (bitonic on packed keys) ->
// gather + cross-attn softmax + LN + FFN(GELU exact) + residual + Wo.
// grid 32, block 1024.
// ---------------------------------------------------------------------------
__global__ __launch_bounds__(1024) void select_finish_kernel(
    const float* __restrict__ sc, const unsigned int* __restrict__ hist,
    const float* __restrict__ emV, const float* __restrict__ qc,
    const float* __restrict__ lng, const float* __restrict__ lnb,
    const float* __restrict__ f1w, const float* __restrict__ f1b,
    const float* __restrict__ f2w, const float* __restrict__ f2b,
    const float* __restrict__ Wo, const float* __restrict__ Wob,
    float* __restrict__ out) {
  const int b = blockIdx.x, t = threadIdx.x;
  const int wave = t >> 6, lane = t & 63;

  __shared__ unsigned int scum[kBins];
  __shared__ int Bsh;
  __shared__ unsigned int cnt;
  __shared__ unsigned long long ck[kCap];
  __shared__ float outvS[32];
  __shared__ int outiS[32];
  __shared__ float Vt[32][128];
  __shared__ float qcl[128];
  __shared__ float wgt[32];
  __shared__ float hS[128];
  __shared__ float y1S[512];
  __shared__ float p2S[4][128];
  __shared__ float o2S[128];
  __shared__ float redA[2];
  __shared__ float redB[2];

  if (t < kBins) scum[t] = hist[b * kBins + t];
  if (t == 0) { Bsh = 0; cnt = 0u; }
  if (t < 128) qcl[t] = qc[b * kDE + t];
  __syncthreads();

  // suffix sum: scum[j] = #scores with bin >= j
  for (int off = 1; off < kBins; off <<= 1) {
    unsigned int v = 0;
    if (t < kBins) {
      v = scum[t];
      if (t + off < kBins) v += scum[t + off];
    }
    __syncthreads();
    if (t < kBins) scum[t] = v;
    __syncthreads();
  }
  if (t < kBins && scum[t] >= 32u) atomicMax(&Bsh, t);
  __syncthreads();
  const int B = Bsh;

  // candidate compaction: packed key = (monotone(score) << 32) | ~idx
  const float* scb = sc + (size_t)b * kM;
#pragma unroll
  for (int j = 0; j < 32; ++j) {
    const int idx = j * 1024 + t;
    const float s = scb[idx];
    if (score_bin(s) >= B) {
      const unsigned int pos = atomicAdd(&cnt, 1u);
      if (pos < (unsigned)kCap) {
        unsigned int u = __float_as_uint(s);
        u = (u & 0x80000000u) ? ~u : (u | 0x80000000u);
        ck[pos] = ((unsigned long long)u << 32) | (unsigned int)(~idx);
      }
    }
  }
  __syncthreads();
  const unsigned int total = cnt;
  for (unsigned int i = t; i < (unsigned)kCap; i += 1024)
    if (i >= total) ck[i] = 0ull;
  __syncthreads();

  // bitonic sort descending over kCap keys
  for (int k2 = 2; k2 <= kCap; k2 <<= 1) {
    for (int j2 = k2 >> 1; j2 > 0; j2 >>= 1) {
      const int l = t ^ j2;
      if (l > t) {
        const unsigned long long a = ck[t], c = ck[l];
        const bool desc = ((t & k2) == 0);
        if ((a < c) == desc) { ck[t] = c; ck[l] = a; }
      }
      __syncthreads();
    }
  }

  if (t < 32) {
    const unsigned long long kk = ck[t];
    const unsigned int mono = (unsigned int)(kk >> 32);
    const unsigned int u = (mono & 0x80000000u) ? (mono & 0x7fffffffu) : ~mono;
    outvS[t] = __uint_as_float(u);
    outiS[t] = (int)(~(unsigned int)kk);
  }
  __syncthreads();

  // gather V_top (32 rows x 128)
  const float* Vb = emV + (size_t)b * kM * kDE;
#pragma unroll
  for (int e = t; e < 32 * 128; e += 1024) {
    const int r = e >> 7, ccol = e & 127;
    Vt[r][ccol] = Vb[(size_t)outiS[r] * kDE + ccol];
  }
  __syncthreads();

  // attention logits: 16 waves x 2 rows
#pragma unroll
  for (int kk2 = 0; kk2 < 2; ++kk2) {
    const int k = wave * 2 + kk2;
    float p = Vt[k][2 * lane] * qcl[2 * lane] + Vt[k][2 * lane + 1] * qcl[2 * lane + 1];
#pragma unroll
    for (int m = 1; m < 64; m <<= 1) p += __shfl_xor(p, m);
    if (lane == 0) {
      const float tv = outvS[k];
      wgt[k] = (tv == -INFINITY) ? -INFINITY : fmaf(p, 0.08838834764831845f, tv);
    }
  }
  __syncthreads();

  // softmax over 32 logits (nan_to_num semantics)
  if (t < 32) {
    const float lg = wgt[t];
    float mx = lg;
#pragma unroll
    for (int m = 1; m < 32; m <<= 1) mx = fmaxf(mx, __shfl_xor(mx, m));
    float e = (mx == -INFINITY || lg == -INFINITY) ? 0.f : __expf(lg - mx);
    float ssum = e;
#pragma unroll
    for (int m = 1; m < 32; m <<= 1) ssum += __shfl_xor(ssum, m);
    wgt[t] = (ssum > 0.f) ? e / ssum : 0.f;
  }
  __syncthreads();

  // out = sum_k w_k V_k (t < 128), then LayerNorm
  float od = 0.f;
  if (t < 128) {
#pragma unroll 8
    for (int k = 0; k < 32; ++k) od += wgt[k] * Vt[k][t];
  }
  float s1 = (t < 128) ? od : 0.f;
  float s2 = (t < 128) ? od * od : 0.f;
#pragma unroll
  for (int m = 1; m < 64; m <<= 1) {
    s1 += __shfl_xor(s1, m);
    s2 += __shfl_xor(s2, m);
  }
  if (lane == 0 && wave < 2) { redA[wave] = s1; redB[wave] = s2; }
  __syncthreads();
  const float sum1 = redA[0] + redA[1];
  const float sum2 = redB[0] + redB[1];
  const float mu = sum1 * (1.f / 128.f);
  const float var = sum2 * (1.f / 128.f) - mu * mu;
  const float rstd = 1.f / sqrtf(var + 1e-5f);
  if (t < 128) hS[t] = (od - mu) * rstd * lng[t] + lnb[t];
  __syncthreads();

  // FFN1 + exact GELU
  if (t < 512) {
    float acc = f1b[t];
#pragma unroll 8
    for (int d = 0; d < 128; ++d) acc += hS[d] * f1w[(size_t)d * 512 + t];
    y1S[t] = 0.5f * acc * (1.f + erff(acc * 0.7071067811865476f));
  }
  __syncthreads();

  // FFN2 split-K (4 slices of 128)
  if (t < 512) {
    const int g = t >> 7, ccol = t & 127;
    float acc = 0.f;
#pragma unroll 8
    for (int jj = 0; jj < 128; ++jj)
      acc += y1S[g * 128 + jj] * f2w[(size_t)(g * 128 + jj) * 128 + ccol];
    p2S[g][ccol] = acc;
  }
  __syncthreads();
  if (t < 128)
    o2S[t] = od + f2b[t] + ((p2S[0][t] + p2S[1][t]) + (p2S[2][t] + p2S[3][t]));
  __syncthreads();

  // final projection: 1024 outputs, one per thread
  float acc = Wob[t];
#pragma unroll 8
  for (int d = 0; d < 128; ++d) acc += o2S[d] * Wo[(size_t)d * kD + t];
  out[(size_t)b * kD + t] = acc;
}

// ---------------------------------------------------------------------------
extern "C" void kernel_launch(void* const* d_in, const int* in_sizes, int n_in,
                              void* d_out, int out_size, void* d_ws, size_t ws_size,
                              hipStream_t stream) {
  const float* x   = (const float*)d_in[0];
  const float* y   = (const float*)d_in[1];
  const float* emK = (const float*)d_in[2];
  const float* emV = (const float*)d_in[3];
  const float* emS = (const float*)d_in[4];
  const float* Wqe = (const float*)d_in[5];
  const float* bqe = (const float*)d_in[6];
  const float* Wqc = (const float*)d_in[7];
  const float* bqc = (const float*)d_in[8];
  const float* Wo  = (const float*)d_in[9];
  const float* Wob = (const float*)d_in[10];
  const float* lng = (const float*)d_in[11];
  const float* lnb = (const float*)d_in[12];
  const float* f1w = (const float*)d_in[13];
  const float* f1b = (const float*)d_in[14];
  const float* f2w = (const float*)d_in[15];
  const float* f2b = (const float*)d_in[16];
  float* out = (float*)d_out;

  float* ws = (float*)d_ws;
  float* q    = ws;                         // 32*128
  float* qc   = ws + 4096;                  // 32*128
  float* sc   = ws + 8192;                  // 32*32768
  unsigned int* hist = (unsigned int*)(ws + 8192 + 32 * kM);  // 32*256 u32

  hipLaunchKernelGGL(qproj_kernel, dim3(32), dim3(1024), 0, stream,
                     x, y, Wqe, bqe, Wqc, bqc, q, qc, hist);
  hipLaunchKernelGGL(scores_kernel, dim3(64, 32), dim3(256), 0, stream,
                     emK, emS, q, sc, hist);
  hipLaunchKernelGGL(select_finish_kernel, dim3(32), dim3(1024), 0, stream,
                     sc, hist, emV, qc, lng, lnb, f1w, f1b, f2w, f2b, Wo, Wob, out);
}